// Round 6
// baseline (307.129 us; speedup 1.0000x reference)
//
#include <hip/hip_runtime.h>
#include <cstdint>

#define Bn 64
#define Ln 512
#define Hn 768
#define Tn 16
#define Cn 8      // chunks over L
#define Sn 64     // chunk length
#define Kn 4      // K-split for GEMM
#define Kc 192    // K-slice per GEMM block (768/4)
#define Mrows (Bn*Ln)   // 32768
#define LOG16 2.7725887222397812f

// ---------------- K_A: partial GEMM, split-K, r0 structure + W-in-LDS ----------------
// (unchanged from r5: 0 conflicts, FETCH 49MB, WRITE 8.2MB; W broadcast via LDS)
// Only delta: also zero bdone[64] for the em_scan last-block-wins ticket.
// k-accumulation order IDENTICAL to lineage -> partial/em BIT-IDENTICAL.
__global__ __launch_bounds__(256) void k_gemm_part(
    const float* __restrict__ hs, const float* __restrict__ W,
    float* __restrict__ partial, float* __restrict__ lossws) {
  int bx = blockIdx.x;
  int tid = threadIdx.x;
  if (bx == 0) {                           // zero loss accum + ticket + bdone each iter
    if (tid == 0) { lossws[0] = 0.f; ((int*)lossws)[1] = 0; }
    if (tid < Bn) ((int*)(lossws + 64))[tid] = 0;   // bdone @ lossws+256B
  }
  int rt = bx >> 2, s = bx & 3;
  int r0 = rt * 128, kb = s * Kc;
  int row = (tid & 63) + ((tid >> 7) << 6);   // waves 0,1 -> rows 0-63; waves 2,3 -> 64-127
  int t0 = ((tid >> 6) & 1) * 8;              // wave-uniform t-half
  __shared__ float alds[128 * 36];            // 18,432 B; stride 36 (0 conflicts measured)
  __shared__ float wlds[16 * 192];            // 12,288 B; W slice, broadcast-read
  float acc[8] = {0.f};
  // stage W slice once (768 float4, 3 per thread, coalesced 16B runs per t-row)
  for (int idx = tid; idx < 768; idx += 256) {
    int t = idx / 48, jj = idx - t * 48;
    *(float4*)&wlds[t * 192 + jj * 4] = *(const float4*)(W + (size_t)t * Hn + kb + jj * 4);
  }
#pragma unroll 1
  for (int cc = 0; cc < 6; ++cc) {            // 6 sub-chunks of 32 K-floats
    int k0 = kb + cc * 32;
#pragma unroll
    for (int it = 0; it < 4; ++it) {          // 1024 float4: 128 rows x 8 slots
      int f = it * 256 + tid;
      int r = f >> 3, j = f & 7;              // 128B contiguous run per row
      float4 v = *(const float4*)(hs + (size_t)(r0 + r) * Hn + k0 + j * 4);
      *(float4*)&alds[r * 36 + j * 4] = v;
    }
    __syncthreads();                          // covers W staging at cc=0 too
#pragma unroll
    for (int j = 0; j < 8; ++j) {
      float4 a = *(const float4*)&alds[row * 36 + j * 4];
#pragma unroll
      for (int tt = 0; tt < 8; ++tt) {
        float4 wv = *(const float4*)&wlds[(t0 + tt) * 192 + cc * 32 + j * 4];  // broadcast
        acc[tt] = fmaf(a.x, wv.x, fmaf(a.y, wv.y, fmaf(a.z, wv.z, fmaf(a.w, wv.w, acc[tt]))));
      }
    }
    __syncthreads();
  }
  float* dst = partial + ((size_t)s * Mrows + (r0 + row)) * Tn + t0;
  *(float4*)(dst + 0) = make_float4(acc[0], acc[1], acc[2], acc[3]);
  *(float4*)(dst + 4) = make_float4(acc[4], acc[5], acc[6], acc[7]);
}

// ---------------- K_B: reduce+em + ONE scan per block + FUSED TAIL (winner) ----------
// blocks 0..511: reduce + denom scan (+em write); 512..1023: reduce + Viterbi.
// NEW: last-block-wins tail fusion.  Each b has 16 blocks (8 denom + 8 vit);
// after storing scan outputs every block does threadfence -> barrier -> tid0
// atomicAdd(bdone[b]); the 16th finisher acquires and runs the full tail for b
// (numer, denom-fold + loss atomic/ticket, vit-fold + backtrack) in-kernel.
// Kills the k_tail launch + its half-idle 128-block grid.  No spins -> no hang.
// Scan phases untouched -> em/qmat/qv/hist bit-identical -> tags unchanged.
__global__ __launch_bounds__(256) void k_em_scan(
    const float* __restrict__ partial, const float* __restrict__ bias,
    const int* __restrict__ mask, const float* __restrict__ trans,
    const int* __restrict__ labels, const float* __restrict__ start,
    const float* __restrict__ endt,
    float* __restrict__ em, float* __restrict__ qmat,
    float* __restrict__ qv, uint8_t* __restrict__ hist,
    float* __restrict__ lossws, float* __restrict__ loss_out,
    float* __restrict__ tags) {
  int half = blockIdx.x >> 9, bc = blockIdx.x & 511;
  int b = bc >> 3, c = bc & 7;
  int tid = threadIdx.x, i = tid >> 4, tp = tid & 15;
  int l0 = c * Sn;
  __shared__ float ems[Sn * Tn];
  __shared__ int msk[Sn];
  __shared__ float pbuf[256];            // per-group broadcast row (16 floats/group)
  __shared__ uint8_t hl[Tn * Sn * Tn];   // 16 KB (used by half 1 only)
  __shared__ int amwin;
  __shared__ float sw[4]; __shared__ int mw[4]; __shared__ float snum;
  __shared__ int Bs[Cn][Tn]; __shared__ int bnd[Cn + 1];
  // phase 0: reduce partial -> em (bit-identical order: bias + s0..s3)
#pragma unroll
  for (int g = 0; g < 4; ++g) {
    int rl = (tid >> 4) + g * 16, t = tid & 15;
    int grow = bc * Sn + rl;
    float sum = bias[t];
#pragma unroll
    for (int s = 0; s < Kn; ++s) sum += partial[((size_t)s * Mrows + grow) * Tn + t];
    float mx = sum;
    mx = fmaxf(mx, __shfl_xor(mx, 1));
    mx = fmaxf(mx, __shfl_xor(mx, 2));
    mx = fmaxf(mx, __shfl_xor(mx, 4));
    mx = fmaxf(mx, __shfl_xor(mx, 8));
    float ev = sum - (mx + LOG16);
    ems[rl * Tn + t] = ev;
    if (half == 0) em[(size_t)grow * Tn + t] = ev;
  }
  if (tid < Sn) msk[tid] = mask[b * Ln + l0 + tid];
  __syncthreads();
  int lstart = (c == 0) ? 1 : l0;
  int gb = i << 4;                       // group base in pbuf (64B aligned)
  if (half == 0) {
    // denominator scan (linear space, renorm every 16); dot chain t=0..15 as before
    float etr[Tn];
#pragma unroll
    for (int t = 0; t < Tn; ++t) etr[t] = __expf(trans[t * Tn + tp]);
    float p = (tp == i) ? 1.f : 0.f;
    float logs = 0.f;
    for (int l = lstart; l < l0 + Sn; ++l) {
      pbuf[tid] = p;
      __builtin_amdgcn_sched_barrier(0);
      float4 q0 = *(const float4*)&pbuf[gb + 0];
      float4 q1 = *(const float4*)&pbuf[gb + 4];
      float4 q2 = *(const float4*)&pbuf[gb + 8];
      float4 q3 = *(const float4*)&pbuf[gb + 12];
      float cs = __expf(ems[(l - l0) * Tn + tp]);
      float dot = 0.f;
      dot = fmaf(q0.x, etr[0],  dot); dot = fmaf(q0.y, etr[1],  dot);
      dot = fmaf(q0.z, etr[2],  dot); dot = fmaf(q0.w, etr[3],  dot);
      dot = fmaf(q1.x, etr[4],  dot); dot = fmaf(q1.y, etr[5],  dot);
      dot = fmaf(q1.z, etr[6],  dot); dot = fmaf(q1.w, etr[7],  dot);
      dot = fmaf(q2.x, etr[8],  dot); dot = fmaf(q2.y, etr[9],  dot);
      dot = fmaf(q2.z, etr[10], dot); dot = fmaf(q2.w, etr[11], dot);
      dot = fmaf(q3.x, etr[12], dot); dot = fmaf(q3.y, etr[13], dot);
      dot = fmaf(q3.z, etr[14], dot); dot = fmaf(q3.w, etr[15], dot);
      float pn = dot * cs;
      p = msk[l - l0] ? pn : p;
      if ((l & 15) == 15) {
        float m = p;
        m = fmaxf(m, __shfl_xor(m, 1));
        m = fmaxf(m, __shfl_xor(m, 2));
        m = fmaxf(m, __shfl_xor(m, 4));
        m = fmaxf(m, __shfl_xor(m, 8));
        p /= m;
        logs += __logf(m);
      }
    }
    qmat[(((size_t)b * Cn + c) * Tn + i) * Tn + tp] = __logf(p) + logs;
  } else {
    // Viterbi scan (max-plus) + history; serial t=0..15, strict > keeps FIRST max
    float tcol[Tn];
#pragma unroll
    for (int t = 0; t < Tn; ++t) tcol[t] = trans[t * Tn + tp];
    float v = (tp == i) ? 0.f : -1e30f;
    for (int l = lstart; l < l0 + Sn; ++l) {
      pbuf[tid] = v;
      __builtin_amdgcn_sched_barrier(0);
      float4 q0 = *(const float4*)&pbuf[gb + 0];
      float4 q1 = *(const float4*)&pbuf[gb + 4];
      float4 q2 = *(const float4*)&pbuf[gb + 8];
      float4 q3 = *(const float4*)&pbuf[gb + 12];
      float best = -3.0e38f; int arg = 0;
#define VSTEP(val, t) { float cand = (val) + tcol[t]; bool g = cand > best; \
                        arg = g ? (t) : arg; best = g ? cand : best; }
      VSTEP(q0.x, 0)  VSTEP(q0.y, 1)  VSTEP(q0.z, 2)  VSTEP(q0.w, 3)
      VSTEP(q1.x, 4)  VSTEP(q1.y, 5)  VSTEP(q1.z, 6)  VSTEP(q1.w, 7)
      VSTEP(q2.x, 8)  VSTEP(q2.y, 9)  VSTEP(q2.z, 10) VSTEP(q2.w, 11)
      VSTEP(q3.x, 12) VSTEP(q3.y, 13) VSTEP(q3.z, 14) VSTEP(q3.w, 15)
#undef VSTEP
      v = best + ems[(l - l0) * Tn + tp];
      hl[(i * Sn + (l - l0)) * Tn + tp] = (uint8_t)arg;
    }
    qv[(((size_t)b * Cn + c) * Tn + i) * Tn + tp] = v;
    __syncthreads();
    const uint4* s4 = (const uint4*)hl;   // coalesced 16KB dump
    uint4* d4 = (uint4*)(hist + (size_t)bc * (Tn * Sn * Tn));
    for (int k = tid; k < (Tn * Sn * Tn) / 16; k += 256) d4[k] = s4[k];
  }
  // ---- ticket: 16th finisher of batch b runs the tail ----
  __threadfence();                       // release: this thread's global writes
  __syncthreads();                       // all threads' fences done
  if (tid == 0) {
    int* bdone = (int*)(lossws + 64);
    amwin = (atomicAdd(&bdone[b], 1) == 15);
  }
  __syncthreads();
  if (!amwin) return;
  __threadfence();                       // acquire: see the other 15 blocks' writes
  // ---- numerator partial sums (256 threads, 2 l's each) ----
  {
    float s = 0.f; int msum = 0;
    for (int l = tid; l < Ln; l += 256) {
      int y = labels[b * Ln + l];
      int m = mask[b * Ln + l];
      msum += m;
      if (l == 0) s += start[y] + em[((size_t)b * Ln) * Tn + y];
      else if (m) s += trans[labels[b * Ln + l - 1] * Tn + y] + em[((size_t)b * Ln + l) * Tn + y];
    }
    for (int off = 32; off; off >>= 1) {
      s += __shfl_down(s, off);
      msum += __shfl_down(msum, off);
    }
    int wid = tid >> 6, ln = tid & 63;
    if (ln == 0) { sw[wid] = s; mw[wid] = msum; }
  }
  __syncthreads();
  if (tid == 0) {
    float st = sw[0] + sw[1] + sw[2] + sw[3];
    int mt = mw[0] + mw[1] + mw[2] + mw[3];
    snum = st + endt[labels[b * Ln + mt - 1]];
  }
  __syncthreads();
  if (tid < Tn) {                        // denom fold over chunk matrices + loss
    int k = tid;
    float p = start[k] + em[((size_t)b * Ln) * Tn + k];
    for (int cc2 = 0; cc2 < Cn; ++cc2) {
      float vals[Tn]; float mx = -3.0e38f;
#pragma unroll
      for (int i2 = 0; i2 < Tn; ++i2) {
        float cand = __shfl(p, i2, 16) + qmat[(((size_t)b * Cn + cc2) * Tn + i2) * Tn + k];
        vals[i2] = cand;
        mx = fmaxf(mx, cand);
      }
      float sm = 0.f;
#pragma unroll
      for (int i2 = 0; i2 < Tn; ++i2) sm += __expf(vals[i2] - mx);
      p = mx + __logf(sm);
    }
    float x = p + endt[k];
    float mx = x;
    mx = fmaxf(mx, __shfl_xor(mx, 1));
    mx = fmaxf(mx, __shfl_xor(mx, 2));
    mx = fmaxf(mx, __shfl_xor(mx, 4));
    mx = fmaxf(mx, __shfl_xor(mx, 8));
    float e = __expf(x - mx);
    e += __shfl_xor(e, 1);
    e += __shfl_xor(e, 2);
    e += __shfl_xor(e, 4);
    e += __shfl_xor(e, 8);
    float denom = mx + __logf(e);
    if (k == 0) {
      atomicAdd(&lossws[0], snum - denom);
      __threadfence();
      int ticket = atomicAdd((int*)lossws + 1, 1);
      if (ticket == Bn - 1) {            // last of the 64 winners finalizes loss
        __threadfence();
        float total = atomicAdd(&lossws[0], 0.f);
        loss_out[0] = -total * (1.0f / Bn);
      }
    }
  }
  // ---- Viterbi fold ----
  if (tid < Tn) {
    int k = tid;
    float p = start[k] + em[((size_t)b * Ln) * Tn + k];
    for (int cc2 = 0; cc2 < Cn; ++cc2) {
      float best = -3.0e38f; int arg = 0;
#pragma unroll
      for (int i2 = 0; i2 < Tn; ++i2) {
        float cand = __shfl(p, i2, 16) + qv[(((size_t)b * Cn + cc2) * Tn + i2) * Tn + k];
        bool g = cand > best;
        arg = g ? i2 : arg;
        best = g ? cand : best;
      }
      Bs[cc2][k] = arg;
      p = best;
    }
    float x = p + endt[k]; int idx = k;  // first-max argmax over k
#pragma unroll
    for (int d = 1; d < 16; d <<= 1) {
      float xo = __shfl_xor(x, d);
      int io = __shfl_xor(idx, d);
      bool take = (xo > x) || (xo == x && io < idx);
      x = take ? xo : x;
      idx = take ? io : idx;
    }
    if (k == 0) bnd[Cn] = idx;
  }
  __syncthreads();
  if (tid == 0) {
    int t = bnd[Cn];
    for (int cc2 = Cn - 1; cc2 >= 0; --cc2) { t = Bs[cc2][t]; bnd[cc2] = t; }
  }
  __syncthreads();
  // ---- parallel backtrack: 4 waves, each does chunks w0 and w0+4 ----
  int w0id = tid >> 6, lane = tid & 63;
#pragma unroll
  for (int hh2 = 0; hh2 < 2; ++hh2) {
    int w = w0id + hh2 * 4;
    int istar = bnd[w];
    int cur = bnd[w + 1];
    int lc0 = w * Sn;
    const uint4* hp = (const uint4*)(hist + ((size_t)(b * Cn + w) * Tn + istar) * (Sn * Tn));
    uint4 hh = hp[lane];
    float mytag = (lane == 63) ? (float)cur : 0.f;
    for (int l = lc0 + 63; l >= lc0 + 1; --l) {
      int sl = l - lc0;
      unsigned w0v = __shfl((int)hh.x, sl);
      unsigned w1v = __shfl((int)hh.y, sl);
      unsigned w2v = __shfl((int)hh.z, sl);
      unsigned w3v = __shfl((int)hh.w, sl);
      unsigned word = (cur < 8) ? ((cur < 4) ? w0v : w1v) : ((cur < 12) ? w2v : w3v);
      cur = (int)((word >> ((cur & 3) * 8)) & 0xff);
      if (lane == sl - 1) mytag = (float)cur;
    }
    tags[(size_t)b * Ln + lc0 + lane] = mytag;
  }
}

extern "C" void kernel_launch(void* const* d_in, const int* in_sizes, int n_in,
                              void* d_out, int out_size, void* d_ws, size_t ws_size,
                              hipStream_t stream) {
  const float* hs     = (const float*)d_in[0];
  const int*   mask   = (const int*)d_in[1];
  const int*   labels = (const int*)d_in[2];
  const float* W      = (const float*)d_in[3];
  const float* bias   = (const float*)d_in[4];
  const float* start  = (const float*)d_in[5];
  const float* endt   = (const float*)d_in[6];
  const float* trans  = (const float*)d_in[7];
  float* out = (float*)d_out;

  // Workspace (~19.9 MB, NO aliasing — partial & hist are concurrently live in K_B):
  //   em      @ 0          : 2,097,152
  //   qmat    @ 2,097,152  :   524,288
  //   qv      @ 2,621,440  :   524,288
  //   lossws  @ 3,145,728  :     4,096  (accum float, ticket int @+4, bdone[64] @+256)
  //   partial @ 3,149,824  : 8,388,608  (4*32768*16*4)
  //   hist    @ 11,538,432 : 8,388,608
  char* ws = (char*)d_ws;
  float*   em      = (float*)(ws);
  float*   qmat    = (float*)(ws + 2097152);
  float*   qv      = (float*)(ws + 2621440);
  float*   lossws  = (float*)(ws + 3145728);
  float*   partial = (float*)(ws + 3149824);
  uint8_t* hist    = (uint8_t*)(ws + 11538432);

  hipLaunchKernelGGL(k_gemm_part, dim3(1024), dim3(256), 0, stream, hs, W, partial, lossws);
  hipLaunchKernelGGL(k_em_scan,   dim3(1024), dim3(256), 0, stream,
                     partial, bias, mask, trans, labels, start, endt,
                     em, qmat, qv, hist, lossws, out, out + 1);
}

// Round 7
// 271.039 us; speedup vs baseline: 1.1332x; 1.1332x over previous
//
#include <hip/hip_runtime.h>
#include <cstdint>

#define Bn 64
#define Ln 512
#define Hn 768
#define Tn 16
#define Cn 8      // chunks over L
#define Sn 64     // chunk length
#define Kc 192    // K-slice (numerics unit; 4 ordered slices = full K)
#define Mrows (Bn*Ln)   // 32768
#define LOG16 2.7725887222397812f

// ---------------- K_A: FULL-K GEMM + bias + max-shift -> em directly ----------------
// r6 lesson: cross-block fences cost >> one launch; revert 3-kernel structure.
// This round: fold split-K back into one block (256 blocks x 128 rows, full 768 K),
// killing the partial round-trip (8MB write + 16MB read) and em_scan's reduce.
// NUMERICS GUARD: 4 separate accumulators acc[s][tt] (s statically unrolled),
// each fed by the exact lineage fmaf nest (cc 0..5, j 0..7, x,y,z,w) over its
// k-slice; combine bias+s0+s1+s2+s3 in lineage reduce order; row-max is exact
// (order-free) -> em BIT-IDENTICAL -> tags unchanged (absmax stays 7.0).
// W fully in LDS (48KB, broadcast reads); A staged via register-prefetch dbuf.
__global__ __launch_bounds__(256) void k_gemm_em(
    const float* __restrict__ hs, const float* __restrict__ W,
    const float* __restrict__ bias, float* __restrict__ em,
    float* __restrict__ lossws) {
  int bx = blockIdx.x;
  int tid = threadIdx.x;
  if (bx == 0 && tid == 0) {               // zero loss accumulator + ticket each iter
    lossws[0] = 0.f;
    ((int*)lossws)[1] = 0;
  }
  int r0 = bx * 128;
  int row = (tid & 63) + ((tid >> 7) << 6);   // waves 0,1 -> rows 0-63; waves 2,3 -> 64-127
  int t0 = ((tid >> 6) & 1) * 8;              // wave-uniform t-half
  __shared__ float alds[128 * 36];            // 18,432 B (stride 36: 0 conflicts, measured)
  __shared__ float wlds[16 * 768];            // 49,152 B: FULL W, broadcast-read
  __shared__ float sums[128 * 17];            // 8,704 B (stride 17: conflict-spread)
  float acc[4][8] = {{0.f}};                  // 4 k-slices kept separate (bit-exact combine)
  // stage full W once: 3072 float4, 12 per thread, 16B runs per t-row
  for (int idx = tid; idx < 3072; idx += 256) {
    int t = idx / 192, jj = idx - t * 192;
    *(float4*)&wlds[t * 768 + jj * 4] = *(const float4*)(W + (size_t)t * Hn + jj * 4);
  }
  // this thread's 4 staging slots (lineage map: f=it*256+tid, r=f>>3, j=f&7)
  int sr[4], sj[4];
#pragma unroll
  for (int it = 0; it < 4; ++it) { int f = it * 256 + tid; sr[it] = f >> 3; sj[it] = f & 7; }
  float4 pv[4];                               // register prefetch buffer (chunk k+1)
#pragma unroll
  for (int it = 0; it < 4; ++it)
    pv[it] = *(const float4*)(hs + (size_t)(r0 + sr[it]) * Hn + sj[it] * 4);   // chunk 0
#pragma unroll
  for (int s = 0; s < 4; ++s) {               // k-slice (STATIC -> acc[s] in registers)
#pragma unroll 1
    for (int cc = 0; cc < 6; ++cc) {          // 24 chunks total, k0 monotonic 0..736
      int k0 = s * Kc + cc * 32;
#pragma unroll
      for (int it = 0; it < 4; ++it)          // commit prefetched regs to LDS
        *(float4*)&alds[sr[it] * 36 + sj[it] * 4] = pv[it];
      __syncthreads();                        // covers W staging before first compute
      if (k0 < 736) {                         // issue next chunk's loads (fly under FMAs)
#pragma unroll
        for (int it = 0; it < 4; ++it)
          pv[it] = *(const float4*)(hs + (size_t)(r0 + sr[it]) * Hn + (k0 + 32) + sj[it] * 4);
      }
#pragma unroll
      for (int j = 0; j < 8; ++j) {           // EXACT lineage nest: j asc, xyzw
        float4 a = *(const float4*)&alds[row * 36 + j * 4];
#pragma unroll
        for (int tt = 0; tt < 8; ++tt) {
          float4 wv = *(const float4*)&wlds[(t0 + tt) * 768 + k0 + j * 4];  // broadcast
          acc[s][tt] = fmaf(a.x, wv.x, fmaf(a.y, wv.y, fmaf(a.z, wv.z, fmaf(a.w, wv.w, acc[s][tt]))));
        }
      }
      __syncthreads();
    }
  }
  // combine in EXACT lineage reduce order: bias, then s0..s3
#pragma unroll
  for (int tt = 0; tt < 8; ++tt) {
    float sum = bias[t0 + tt];
    sum += acc[0][tt]; sum += acc[1][tt]; sum += acc[2][tt]; sum += acc[3][tt];
    sums[row * 17 + t0 + tt] = sum;
  }
  __syncthreads();
  float mx = sums[row * 17 + 0];              // exact max (order-free)
#pragma unroll
  for (int t = 1; t < 16; ++t) mx = fmaxf(mx, sums[row * 17 + t]);
  float mlog = mx + LOG16;
  float* dst = em + (size_t)(r0 + row) * Tn + t0;
  *(float4*)(dst + 0) = make_float4(sums[row * 17 + t0 + 0] - mlog, sums[row * 17 + t0 + 1] - mlog,
                                    sums[row * 17 + t0 + 2] - mlog, sums[row * 17 + t0 + 3] - mlog);
  *(float4*)(dst + 4) = make_float4(sums[row * 17 + t0 + 4] - mlog, sums[row * 17 + t0 + 5] - mlog,
                                    sums[row * 17 + t0 + 6] - mlog, sums[row * 17 + t0 + 7] - mlog);
}

// ---------------- K_B: ONE scan per block (split grid); em loaded, not reduced ------
// blocks 0..511: denom scan; 512..1023: Viterbi.  Phase 0 is now a 4KB coalesced
// em load (reduce moved into K_A).  Scan bodies identical to r5 (pbuf broadcast:
// 1 ds_write + 4 ds_read_b128; serial chains keep exact order) -> qmat/qv/hist
// bit-identical -> tags unchanged.
__global__ __launch_bounds__(256) void k_em_scan(
    const float* __restrict__ em, const int* __restrict__ mask,
    const float* __restrict__ trans, float* __restrict__ qmat,
    float* __restrict__ qv, uint8_t* __restrict__ hist) {
  int half = blockIdx.x >> 9, bc = blockIdx.x & 511;
  int b = bc >> 3, c = bc & 7;
  int tid = threadIdx.x, i = tid >> 4, tp = tid & 15;
  int l0 = c * Sn;
  __shared__ float ems[Sn * Tn];
  __shared__ int msk[Sn];
  __shared__ float pbuf[256];            // per-group broadcast row (16 floats/group)
  __shared__ uint8_t hl[Tn * Sn * Tn];   // 16 KB (used by half 1 only)
  {
    int rl = tid >> 2, q = tid & 3;      // 64 rows x 16 floats = 256 float4, coalesced
    *(float4*)&ems[rl * Tn + q * 4] = *(const float4*)(em + (size_t)(bc * Sn + rl) * Tn + q * 4);
  }
  if (tid < Sn) msk[tid] = mask[b * Ln + l0 + tid];
  __syncthreads();
  int lstart = (c == 0) ? 1 : l0;
  int gb = i << 4;                       // group base in pbuf (64B aligned)
  if (half == 0) {
    // denominator scan (linear space, renorm every 16); dot chain t=0..15 as lineage
    float etr[Tn];
#pragma unroll
    for (int t = 0; t < Tn; ++t) etr[t] = __expf(trans[t * Tn + tp]);
    float p = (tp == i) ? 1.f : 0.f;
    float logs = 0.f;
    for (int l = lstart; l < l0 + Sn; ++l) {
      pbuf[tid] = p;
      __builtin_amdgcn_sched_barrier(0);
      float4 q0 = *(const float4*)&pbuf[gb + 0];
      float4 q1 = *(const float4*)&pbuf[gb + 4];
      float4 q2 = *(const float4*)&pbuf[gb + 8];
      float4 q3 = *(const float4*)&pbuf[gb + 12];
      float cs = __expf(ems[(l - l0) * Tn + tp]);
      float dot = 0.f;
      dot = fmaf(q0.x, etr[0],  dot); dot = fmaf(q0.y, etr[1],  dot);
      dot = fmaf(q0.z, etr[2],  dot); dot = fmaf(q0.w, etr[3],  dot);
      dot = fmaf(q1.x, etr[4],  dot); dot = fmaf(q1.y, etr[5],  dot);
      dot = fmaf(q1.z, etr[6],  dot); dot = fmaf(q1.w, etr[7],  dot);
      dot = fmaf(q2.x, etr[8],  dot); dot = fmaf(q2.y, etr[9],  dot);
      dot = fmaf(q2.z, etr[10], dot); dot = fmaf(q2.w, etr[11], dot);
      dot = fmaf(q3.x, etr[12], dot); dot = fmaf(q3.y, etr[13], dot);
      dot = fmaf(q3.z, etr[14], dot); dot = fmaf(q3.w, etr[15], dot);
      float pn = dot * cs;
      p = msk[l - l0] ? pn : p;
      if ((l & 15) == 15) {
        float m = p;
        m = fmaxf(m, __shfl_xor(m, 1));
        m = fmaxf(m, __shfl_xor(m, 2));
        m = fmaxf(m, __shfl_xor(m, 4));
        m = fmaxf(m, __shfl_xor(m, 8));
        p /= m;
        logs += __logf(m);
      }
    }
    qmat[(((size_t)b * Cn + c) * Tn + i) * Tn + tp] = __logf(p) + logs;
  } else {
    // Viterbi scan (max-plus) + history; serial t=0..15, strict > keeps FIRST max
    float tcol[Tn];
#pragma unroll
    for (int t = 0; t < Tn; ++t) tcol[t] = trans[t * Tn + tp];
    float v = (tp == i) ? 0.f : -1e30f;
    for (int l = lstart; l < l0 + Sn; ++l) {
      pbuf[tid] = v;
      __builtin_amdgcn_sched_barrier(0);
      float4 q0 = *(const float4*)&pbuf[gb + 0];
      float4 q1 = *(const float4*)&pbuf[gb + 4];
      float4 q2 = *(const float4*)&pbuf[gb + 8];
      float4 q3 = *(const float4*)&pbuf[gb + 12];
      float best = -3.0e38f; int arg = 0;
#define VSTEP(val, t) { float cand = (val) + tcol[t]; bool g = cand > best; \
                        arg = g ? (t) : arg; best = g ? cand : best; }
      VSTEP(q0.x, 0)  VSTEP(q0.y, 1)  VSTEP(q0.z, 2)  VSTEP(q0.w, 3)
      VSTEP(q1.x, 4)  VSTEP(q1.y, 5)  VSTEP(q1.z, 6)  VSTEP(q1.w, 7)
      VSTEP(q2.x, 8)  VSTEP(q2.y, 9)  VSTEP(q2.z, 10) VSTEP(q2.w, 11)
      VSTEP(q3.x, 12) VSTEP(q3.y, 13) VSTEP(q3.z, 14) VSTEP(q3.w, 15)
#undef VSTEP
      v = best + ems[(l - l0) * Tn + tp];
      hl[(i * Sn + (l - l0)) * Tn + tp] = (uint8_t)arg;
    }
    qv[(((size_t)b * Cn + c) * Tn + i) * Tn + tp] = v;
    __syncthreads();
    const uint4* s4 = (const uint4*)hl;   // coalesced 16KB dump
    uint4* d4 = (uint4*)(hist + (size_t)bc * (Tn * Sn * Tn));
    for (int k = tid; k < (Tn * Sn * Tn) / 16; k += 256) d4[k] = s4[k];
  }
}

// ---------------- K_C: merged tail (verbatim r5) — viterbi+backtrack (blocks 0..63)
// concurrent with numerator+denom-fold (blocks 64..127); loss via atomic + ticket.
__global__ __launch_bounds__(512) void k_tail(
    const float* __restrict__ qv, const float* __restrict__ em,
    const float* __restrict__ start, const float* __restrict__ endt,
    const uint8_t* __restrict__ hist, const int* __restrict__ labels,
    const int* __restrict__ mask, const float* __restrict__ trans,
    const float* __restrict__ qmat, float* __restrict__ lossws,
    float* __restrict__ loss_out, float* __restrict__ tags) {
  int bid = blockIdx.x, tid = threadIdx.x;
  if (bid >= Bn) {
    // ---- numerator + denominator fold -> llh contribution for b = bid-64 ----
    int b = bid - Bn;
    {
      int l = tid;                         // 512 threads = one l each
      int y = labels[b * Ln + l];
      int m = mask[b * Ln + l];
      float s;
      if (l == 0) s = start[y] + em[((size_t)b * Ln) * Tn + y];
      else s = m ? (trans[labels[b * Ln + l - 1] * Tn + y] + em[((size_t)b * Ln + l) * Tn + y]) : 0.f;
      int msum = m;
      for (int off = 32; off; off >>= 1) {
        s += __shfl_down(s, off);
        msum += __shfl_down(msum, off);
      }
      __shared__ float sw[8]; __shared__ int mw[8];
      __shared__ float snum;
      int wid = tid >> 6, ln = tid & 63;
      if (ln == 0) { sw[wid] = s; mw[wid] = msum; }
      __syncthreads();
      if (tid == 0) {
        float st = 0.f; int mt = 0;
        for (int wv = 0; wv < 8; ++wv) { st += sw[wv]; mt += mw[wv]; }
        snum = st + endt[labels[b * Ln + mt - 1]];
      }
      __syncthreads();
      if (tid < Tn) {                     // 16-lane log-space fold over chunk matrices
        int k = tid;
        float p = start[k] + em[((size_t)b * Ln) * Tn + k];
        for (int c = 0; c < Cn; ++c) {
          float vals[Tn]; float mx = -3.0e38f;
#pragma unroll
          for (int i2 = 0; i2 < Tn; ++i2) {
            float cand = __shfl(p, i2, 16) + qmat[(((size_t)b * Cn + c) * Tn + i2) * Tn + k];
            vals[i2] = cand;
            mx = fmaxf(mx, cand);
          }
          float sm = 0.f;
#pragma unroll
          for (int i2 = 0; i2 < Tn; ++i2) sm += __expf(vals[i2] - mx);
          p = mx + __logf(sm);
        }
        float x = p + endt[k];
        float mx = x;
        mx = fmaxf(mx, __shfl_xor(mx, 1));
        mx = fmaxf(mx, __shfl_xor(mx, 2));
        mx = fmaxf(mx, __shfl_xor(mx, 4));
        mx = fmaxf(mx, __shfl_xor(mx, 8));
        float e = __expf(x - mx);
        e += __shfl_xor(e, 1);
        e += __shfl_xor(e, 2);
        e += __shfl_xor(e, 4);
        e += __shfl_xor(e, 8);
        float denom = mx + __logf(e);
        if (k == 0) {
          atomicAdd(&lossws[0], snum - denom);
          __threadfence();
          int ticket = atomicAdd((int*)lossws + 1, 1);
          if (ticket == Bn - 1) {         // last numer block finalizes loss
            __threadfence();
            float total = atomicAdd(&lossws[0], 0.f);
            loss_out[0] = -total * (1.0f / Bn);
          }
        }
      }
    }
    return;
  }
  // ---- Viterbi fold + parallel backtrack for b = bid ----
  int b = bid;
  __shared__ int Bs[Cn][Tn];
  __shared__ int bnd[Cn + 1];
  if (tid < Tn) {
    int k = tid;
    float p = start[k] + em[((size_t)b * Ln) * Tn + k];
    for (int c = 0; c < Cn; ++c) {
      float best = -3.0e38f; int arg = 0;
#pragma unroll
      for (int i2 = 0; i2 < Tn; ++i2) {
        float cand = __shfl(p, i2, 16) + qv[(((size_t)b * Cn + c) * Tn + i2) * Tn + k];
        bool g = cand > best;
        arg = g ? i2 : arg;
        best = g ? cand : best;
      }
      Bs[c][k] = arg;
      p = best;
    }
    float x = p + endt[k]; int idx = k;   // first-max argmax over k
#pragma unroll
    for (int d = 1; d < 16; d <<= 1) {
      float xo = __shfl_xor(x, d);
      int io = __shfl_xor(idx, d);
      bool take = (xo > x) || (xo == x && io < idx);
      x = take ? xo : x;
      idx = take ? io : idx;
    }
    if (k == 0) bnd[Cn] = idx;
  }
  __syncthreads();
  if (tid == 0) {
    int t = bnd[Cn];
    for (int c = Cn - 1; c >= 0; --c) { t = Bs[c][t]; bnd[c] = t; }
  }
  __syncthreads();
  int w = tid >> 6, lane = tid & 63;      // wave w backtracks chunk w
  int istar = bnd[w];
  int cur = bnd[w + 1];
  int l0 = w * Sn;
  const uint4* hp = (const uint4*)(hist + ((size_t)(b * Cn + w) * Tn + istar) * (Sn * Tn));
  uint4 hh = hp[lane];
  float mytag = (lane == 63) ? (float)cur : 0.f;
  for (int l = l0 + 63; l >= l0 + 1; --l) {
    int sl = l - l0;
    unsigned w0 = __shfl((int)hh.x, sl);
    unsigned w1 = __shfl((int)hh.y, sl);
    unsigned w2 = __shfl((int)hh.z, sl);
    unsigned w3 = __shfl((int)hh.w, sl);
    unsigned word = (cur < 8) ? ((cur < 4) ? w0 : w1) : ((cur < 12) ? w2 : w3);
    cur = (int)((word >> ((cur & 3) * 8)) & 0xff);
    if (lane == sl - 1) mytag = (float)cur;
  }
  tags[(size_t)b * Ln + l0 + lane] = mytag;
}

extern "C" void kernel_launch(void* const* d_in, const int* in_sizes, int n_in,
                              void* d_out, int out_size, void* d_ws, size_t ws_size,
                              hipStream_t stream) {
  const float* hs     = (const float*)d_in[0];
  const int*   mask   = (const int*)d_in[1];
  const int*   labels = (const int*)d_in[2];
  const float* W      = (const float*)d_in[3];
  const float* bias   = (const float*)d_in[4];
  const float* start  = (const float*)d_in[5];
  const float* endt   = (const float*)d_in[6];
  const float* trans  = (const float*)d_in[7];
  float* out = (float*)d_out;

  // Workspace (~11.5 MB; partial ELIMINATED — em written directly by K_A):
  //   em      @ 0          : 2,097,152
  //   qmat    @ 2,097,152  :   524,288
  //   qv      @ 2,621,440  :   524,288
  //   lossws  @ 3,145,728  :     4,096  (accum float + ticket int)
  //   hist    @ 3,149,824  : 8,388,608
  char* ws = (char*)d_ws;
  float*   em      = (float*)(ws);
  float*   qmat    = (float*)(ws + 2097152);
  float*   qv      = (float*)(ws + 2621440);
  float*   lossws  = (float*)(ws + 3145728);
  uint8_t* hist    = (uint8_t*)(ws + 3149824);

  hipLaunchKernelGGL(k_gemm_em, dim3(256),  dim3(256), 0, stream, hs, W, bias, em, lossws);
  hipLaunchKernelGGL(k_em_scan, dim3(1024), dim3(256), 0, stream, em, mask, trans, qmat, qv, hist);
  hipLaunchKernelGGL(k_tail,    dim3(128),  dim3(512), 0, stream, qv, em, start, endt, hist, labels, mask, trans, qmat, lossws, out, out + 1);
}

// Round 8
// 221.182 us; speedup vs baseline: 1.3886x; 1.2254x over previous
//
#include <hip/hip_runtime.h>
#include <cstdint>

#define Bn 64
#define Ln 512
#define Hn 768
#define Tn 16
#define Cn 8      // chunks over L
#define Sn 64     // chunk length
#define Kn 4      // K-split for GEMM
#define Kc 192    // K-slice per GEMM block (768/4)
#define Mrows (Bn*Ln)   // 32768
#define LOG16 2.7725887222397812f

// ---------------- K_A: partial GEMM, split-K, W-in-LDS + register prefetch ----------
// r7 lesson: full-K fold -> 1 block/CU -> no latency hiding (Occ 10.8%, 116us).
// Split-K restored (1024 blocks = 4/CU, r5 measured-good) + r7's reg-prefetch:
// chunk cc+1's 4 global float4s issue right after the staging barrier, hiding
// HBM latency under chunk cc's 512 FMAs instead of at the next vmcnt drain.
// Staging map, k-order (kb+cc*32, j asc, xyzw) and store path are lineage-exact
// -> partial/em BIT-IDENTICAL -> tags unchanged.
__global__ __launch_bounds__(256) void k_gemm_part(
    const float* __restrict__ hs, const float* __restrict__ W,
    float* __restrict__ partial, float* __restrict__ lossws) {
  int bx = blockIdx.x;
  int tid = threadIdx.x;
  if (bx == 0 && tid == 0) {               // zero loss accumulator + ticket each iter
    lossws[0] = 0.f;
    ((int*)lossws)[1] = 0;
  }
  int rt = bx >> 2, s = bx & 3;
  int r0 = rt * 128, kb = s * Kc;
  int row = (tid & 63) + ((tid >> 7) << 6);   // waves 0,1 -> rows 0-63; waves 2,3 -> 64-127
  int t0 = ((tid >> 6) & 1) * 8;              // wave-uniform t-half
  __shared__ float alds[128 * 36];            // 18,432 B (stride 36: 0 conflicts measured)
  __shared__ float wlds[16 * 192];            // 12,288 B: W slice, broadcast-read
  float acc[8] = {0.f};
  // stage W slice once (768 float4, 3/thread, 16B runs per t-row)
  for (int idx = tid; idx < 768; idx += 256) {
    int t = idx / 48, jj = idx - t * 48;
    *(float4*)&wlds[t * 192 + jj * 4] = *(const float4*)(W + (size_t)t * Hn + kb + jj * 4);
  }
  // this thread's 4 staging slots (lineage map: f=it*256+tid, r=f>>3, j=f&7)
  int sr[4], sj[4];
#pragma unroll
  for (int it = 0; it < 4; ++it) { int f = it * 256 + tid; sr[it] = f >> 3; sj[it] = f & 7; }
  float4 pv[4];                               // register prefetch buffer (next chunk)
#pragma unroll
  for (int it = 0; it < 4; ++it)
    pv[it] = *(const float4*)(hs + (size_t)(r0 + sr[it]) * Hn + kb + sj[it] * 4);  // chunk 0
#pragma unroll 1
  for (int cc = 0; cc < 6; ++cc) {            // 6 sub-chunks of 32 K-floats
    int k0 = kb + cc * 32;
#pragma unroll
    for (int it = 0; it < 4; ++it)            // commit prefetched regs to LDS
      *(float4*)&alds[sr[it] * 36 + sj[it] * 4] = pv[it];
    __syncthreads();                          // covers W staging at cc=0 too
    if (cc < 5) {                             // issue next chunk's loads under the FMAs
#pragma unroll
      for (int it = 0; it < 4; ++it)
        pv[it] = *(const float4*)(hs + (size_t)(r0 + sr[it]) * Hn + (k0 + 32) + sj[it] * 4);
    }
#pragma unroll
    for (int j = 0; j < 8; ++j) {             // EXACT lineage nest: j asc, xyzw
      float4 a = *(const float4*)&alds[row * 36 + j * 4];
#pragma unroll
      for (int tt = 0; tt < 8; ++tt) {
        float4 wv = *(const float4*)&wlds[(t0 + tt) * 192 + cc * 32 + j * 4];  // broadcast
        acc[tt] = fmaf(a.x, wv.x, fmaf(a.y, wv.y, fmaf(a.z, wv.z, fmaf(a.w, wv.w, acc[tt]))));
      }
    }
    __syncthreads();
  }
  float* dst = partial + ((size_t)s * Mrows + (r0 + row)) * Tn + t0;
  *(float4*)(dst + 0) = make_float4(acc[0], acc[1], acc[2], acc[3]);
  *(float4*)(dst + 4) = make_float4(acc[4], acc[5], acc[6], acc[7]);
}

// ---------------- K_B: reduce+em, then ONE scan per block (r5 form, verbatim) -------
// blocks 0..511: reduce + denom scan (+em write); 512..1023: reduce + Viterbi.
// pbuf broadcast: 1 ds_write + 4 ds_read_b128 per step; serial chains keep exact
// order -> qmat/qv/hist bit-identical -> tags unchanged.
__global__ __launch_bounds__(256) void k_em_scan(
    const float* __restrict__ partial, const float* __restrict__ bias,
    const int* __restrict__ mask, const float* __restrict__ trans,
    float* __restrict__ em, float* __restrict__ qmat,
    float* __restrict__ qv, uint8_t* __restrict__ hist) {
  int half = blockIdx.x >> 9, bc = blockIdx.x & 511;
  int b = bc >> 3, c = bc & 7;
  int tid = threadIdx.x, i = tid >> 4, tp = tid & 15;
  int l0 = c * Sn;
  __shared__ float ems[Sn * Tn];
  __shared__ int msk[Sn];
  __shared__ float pbuf[256];            // per-group broadcast row (16 floats/group)
  __shared__ uint8_t hl[Tn * Sn * Tn];   // 16 KB (used by half 1 only)
  // phase 0: reduce partial -> em (bit-identical order: bias + s0..s3)
#pragma unroll
  for (int g = 0; g < 4; ++g) {
    int rl = (tid >> 4) + g * 16, t = tid & 15;
    int grow = bc * Sn + rl;
    float sum = bias[t];
#pragma unroll
    for (int s = 0; s < Kn; ++s) sum += partial[((size_t)s * Mrows + grow) * Tn + t];
    float mx = sum;
    mx = fmaxf(mx, __shfl_xor(mx, 1));
    mx = fmaxf(mx, __shfl_xor(mx, 2));
    mx = fmaxf(mx, __shfl_xor(mx, 4));
    mx = fmaxf(mx, __shfl_xor(mx, 8));
    float ev = sum - (mx + LOG16);
    ems[rl * Tn + t] = ev;
    if (half == 0) em[(size_t)grow * Tn + t] = ev;
  }
  if (tid < Sn) msk[tid] = mask[b * Ln + l0 + tid];
  __syncthreads();
  int lstart = (c == 0) ? 1 : l0;
  int gb = i << 4;                       // group base in pbuf (64B aligned)
  if (half == 0) {
    // denominator scan (linear space, renorm every 16); dot chain t=0..15 as lineage
    float etr[Tn];
#pragma unroll
    for (int t = 0; t < Tn; ++t) etr[t] = __expf(trans[t * Tn + tp]);
    float p = (tp == i) ? 1.f : 0.f;
    float logs = 0.f;
    for (int l = lstart; l < l0 + Sn; ++l) {
      pbuf[tid] = p;
      __builtin_amdgcn_sched_barrier(0);
      float4 q0 = *(const float4*)&pbuf[gb + 0];
      float4 q1 = *(const float4*)&pbuf[gb + 4];
      float4 q2 = *(const float4*)&pbuf[gb + 8];
      float4 q3 = *(const float4*)&pbuf[gb + 12];
      float cs = __expf(ems[(l - l0) * Tn + tp]);
      float dot = 0.f;
      dot = fmaf(q0.x, etr[0],  dot); dot = fmaf(q0.y, etr[1],  dot);
      dot = fmaf(q0.z, etr[2],  dot); dot = fmaf(q0.w, etr[3],  dot);
      dot = fmaf(q1.x, etr[4],  dot); dot = fmaf(q1.y, etr[5],  dot);
      dot = fmaf(q1.z, etr[6],  dot); dot = fmaf(q1.w, etr[7],  dot);
      dot = fmaf(q2.x, etr[8],  dot); dot = fmaf(q2.y, etr[9],  dot);
      dot = fmaf(q2.z, etr[10], dot); dot = fmaf(q2.w, etr[11], dot);
      dot = fmaf(q3.x, etr[12], dot); dot = fmaf(q3.y, etr[13], dot);
      dot = fmaf(q3.z, etr[14], dot); dot = fmaf(q3.w, etr[15], dot);
      float pn = dot * cs;
      p = msk[l - l0] ? pn : p;
      if ((l & 15) == 15) {
        float m = p;
        m = fmaxf(m, __shfl_xor(m, 1));
        m = fmaxf(m, __shfl_xor(m, 2));
        m = fmaxf(m, __shfl_xor(m, 4));
        m = fmaxf(m, __shfl_xor(m, 8));
        p /= m;
        logs += __logf(m);
      }
    }
    qmat[(((size_t)b * Cn + c) * Tn + i) * Tn + tp] = __logf(p) + logs;
  } else {
    // Viterbi scan (max-plus) + history; serial t=0..15, strict > keeps FIRST max
    float tcol[Tn];
#pragma unroll
    for (int t = 0; t < Tn; ++t) tcol[t] = trans[t * Tn + tp];
    float v = (tp == i) ? 0.f : -1e30f;
    for (int l = lstart; l < l0 + Sn; ++l) {
      pbuf[tid] = v;
      __builtin_amdgcn_sched_barrier(0);
      float4 q0 = *(const float4*)&pbuf[gb + 0];
      float4 q1 = *(const float4*)&pbuf[gb + 4];
      float4 q2 = *(const float4*)&pbuf[gb + 8];
      float4 q3 = *(const float4*)&pbuf[gb + 12];
      float best = -3.0e38f; int arg = 0;
#define VSTEP(val, t) { float cand = (val) + tcol[t]; bool g = cand > best; \
                        arg = g ? (t) : arg; best = g ? cand : best; }
      VSTEP(q0.x, 0)  VSTEP(q0.y, 1)  VSTEP(q0.z, 2)  VSTEP(q0.w, 3)
      VSTEP(q1.x, 4)  VSTEP(q1.y, 5)  VSTEP(q1.z, 6)  VSTEP(q1.w, 7)
      VSTEP(q2.x, 8)  VSTEP(q2.y, 9)  VSTEP(q2.z, 10) VSTEP(q2.w, 11)
      VSTEP(q3.x, 12) VSTEP(q3.y, 13) VSTEP(q3.z, 14) VSTEP(q3.w, 15)
#undef VSTEP
      v = best + ems[(l - l0) * Tn + tp];
      hl[(i * Sn + (l - l0)) * Tn + tp] = (uint8_t)arg;
    }
    qv[(((size_t)b * Cn + c) * Tn + i) * Tn + tp] = v;
    __syncthreads();
    const uint4* s4 = (const uint4*)hl;   // coalesced 16KB dump
    uint4* d4 = (uint4*)(hist + (size_t)bc * (Tn * Sn * Tn));
    for (int k = tid; k < (Tn * Sn * Tn) / 16; k += 256) d4[k] = s4[k];
  }
}

// ---------------- K_C: merged tail (verbatim r5) — viterbi+backtrack (blocks 0..63)
// concurrent with numerator+denom-fold (blocks 64..127); loss via atomic + ticket.
__global__ __launch_bounds__(512) void k_tail(
    const float* __restrict__ qv, const float* __restrict__ em,
    const float* __restrict__ start, const float* __restrict__ endt,
    const uint8_t* __restrict__ hist, const int* __restrict__ labels,
    const int* __restrict__ mask, const float* __restrict__ trans,
    const float* __restrict__ qmat, float* __restrict__ lossws,
    float* __restrict__ loss_out, float* __restrict__ tags) {
  int bid = blockIdx.x, tid = threadIdx.x;
  if (bid >= Bn) {
    // ---- numerator + denominator fold -> llh contribution for b = bid-64 ----
    int b = bid - Bn;
    {
      int l = tid;                         // 512 threads = one l each
      int y = labels[b * Ln + l];
      int m = mask[b * Ln + l];
      float s;
      if (l == 0) s = start[y] + em[((size_t)b * Ln) * Tn + y];
      else s = m ? (trans[labels[b * Ln + l - 1] * Tn + y] + em[((size_t)b * Ln + l) * Tn + y]) : 0.f;
      int msum = m;
      for (int off = 32; off; off >>= 1) {
        s += __shfl_down(s, off);
        msum += __shfl_down(msum, off);
      }
      __shared__ float sw[8]; __shared__ int mw[8];
      __shared__ float snum;
      int wid = tid >> 6, ln = tid & 63;
      if (ln == 0) { sw[wid] = s; mw[wid] = msum; }
      __syncthreads();
      if (tid == 0) {
        float st = 0.f; int mt = 0;
        for (int wv = 0; wv < 8; ++wv) { st += sw[wv]; mt += mw[wv]; }
        snum = st + endt[labels[b * Ln + mt - 1]];
      }
      __syncthreads();
      if (tid < Tn) {                     // 16-lane log-space fold over chunk matrices
        int k = tid;
        float p = start[k] + em[((size_t)b * Ln) * Tn + k];
        for (int c = 0; c < Cn; ++c) {
          float vals[Tn]; float mx = -3.0e38f;
#pragma unroll
          for (int i2 = 0; i2 < Tn; ++i2) {
            float cand = __shfl(p, i2, 16) + qmat[(((size_t)b * Cn + c) * Tn + i2) * Tn + k];
            vals[i2] = cand;
            mx = fmaxf(mx, cand);
          }
          float sm = 0.f;
#pragma unroll
          for (int i2 = 0; i2 < Tn; ++i2) sm += __expf(vals[i2] - mx);
          p = mx + __logf(sm);
        }
        float x = p + endt[k];
        float mx = x;
        mx = fmaxf(mx, __shfl_xor(mx, 1));
        mx = fmaxf(mx, __shfl_xor(mx, 2));
        mx = fmaxf(mx, __shfl_xor(mx, 4));
        mx = fmaxf(mx, __shfl_xor(mx, 8));
        float e = __expf(x - mx);
        e += __shfl_xor(e, 1);
        e += __shfl_xor(e, 2);
        e += __shfl_xor(e, 4);
        e += __shfl_xor(e, 8);
        float denom = mx + __logf(e);
        if (k == 0) {
          atomicAdd(&lossws[0], snum - denom);
          __threadfence();
          int ticket = atomicAdd((int*)lossws + 1, 1);
          if (ticket == Bn - 1) {         // last numer block finalizes loss
            __threadfence();
            float total = atomicAdd(&lossws[0], 0.f);
            loss_out[0] = -total * (1.0f / Bn);
          }
        }
      }
    }
    return;
  }
  // ---- Viterbi fold + parallel backtrack for b = bid ----
  int b = bid;
  __shared__ int Bs[Cn][Tn];
  __shared__ int bnd[Cn + 1];
  if (tid < Tn) {
    int k = tid;
    float p = start[k] + em[((size_t)b * Ln) * Tn + k];
    for (int c = 0; c < Cn; ++c) {
      float best = -3.0e38f; int arg = 0;
#pragma unroll
      for (int i2 = 0; i2 < Tn; ++i2) {
        float cand = __shfl(p, i2, 16) + qv[(((size_t)b * Cn + c) * Tn + i2) * Tn + k];
        bool g = cand > best;
        arg = g ? i2 : arg;
        best = g ? cand : best;
      }
      Bs[c][k] = arg;
      p = best;
    }
    float x = p + endt[k]; int idx = k;   // first-max argmax over k
#pragma unroll
    for (int d = 1; d < 16; d <<= 1) {
      float xo = __shfl_xor(x, d);
      int io = __shfl_xor(idx, d);
      bool take = (xo > x) || (xo == x && io < idx);
      x = take ? xo : x;
      idx = take ? io : idx;
    }
    if (k == 0) bnd[Cn] = idx;
  }
  __syncthreads();
  if (tid == 0) {
    int t = bnd[Cn];
    for (int c = Cn - 1; c >= 0; --c) { t = Bs[c][t]; bnd[c] = t; }
  }
  __syncthreads();
  int w = tid >> 6, lane = tid & 63;      // wave w backtracks chunk w
  int istar = bnd[w];
  int cur = bnd[w + 1];
  int l0 = w * Sn;
  const uint4* hp = (const uint4*)(hist + ((size_t)(b * Cn + w) * Tn + istar) * (Sn * Tn));
  uint4 hh = hp[lane];
  float mytag = (lane == 63) ? (float)cur : 0.f;
  for (int l = l0 + 63; l >= l0 + 1; --l) {
    int sl = l - l0;
    unsigned w0 = __shfl((int)hh.x, sl);
    unsigned w1 = __shfl((int)hh.y, sl);
    unsigned w2 = __shfl((int)hh.z, sl);
    unsigned w3 = __shfl((int)hh.w, sl);
    unsigned word = (cur < 8) ? ((cur < 4) ? w0 : w1) : ((cur < 12) ? w2 : w3);
    cur = (int)((word >> ((cur & 3) * 8)) & 0xff);
    if (lane == sl - 1) mytag = (float)cur;
  }
  tags[(size_t)b * Ln + l0 + lane] = mytag;
}

extern "C" void kernel_launch(void* const* d_in, const int* in_sizes, int n_in,
                              void* d_out, int out_size, void* d_ws, size_t ws_size,
                              hipStream_t stream) {
  const float* hs     = (const float*)d_in[0];
  const int*   mask   = (const int*)d_in[1];
  const int*   labels = (const int*)d_in[2];
  const float* W      = (const float*)d_in[3];
  const float* bias   = (const float*)d_in[4];
  const float* start  = (const float*)d_in[5];
  const float* endt   = (const float*)d_in[6];
  const float* trans  = (const float*)d_in[7];
  float* out = (float*)d_out;

  // Workspace (~19.9 MB, NO aliasing — partial & hist are concurrently live in K_B):
  //   em      @ 0          : 2,097,152
  //   qmat    @ 2,097,152  :   524,288
  //   qv      @ 2,621,440  :   524,288
  //   lossws  @ 3,145,728  :     4,096  (accum float + ticket int)
  //   partial @ 3,149,824  : 8,388,608  (4*32768*16*4)
  //   hist    @ 11,538,432 : 8,388,608
  char* ws = (char*)d_ws;
  float*   em      = (float*)(ws);
  float*   qmat    = (float*)(ws + 2097152);
  float*   qv      = (float*)(ws + 2621440);
  float*   lossws  = (float*)(ws + 3145728);
  float*   partial = (float*)(ws + 3149824);
  uint8_t* hist    = (uint8_t*)(ws + 11538432);

  hipLaunchKernelGGL(k_gemm_part, dim3(1024), dim3(256), 0, stream, hs, W, partial, lossws);
  hipLaunchKernelGGL(k_em_scan,   dim3(1024), dim3(256), 0, stream, partial, bias, mask, trans, em, qmat, qv, hist);
  hipLaunchKernelGGL(k_tail,      dim3(128),  dim3(512), 0, stream, qv, em, start, endt, hist, labels, mask, trans, qmat, lossws, out, out + 1);
}